// Round 1
// baseline (2805.450 us; speedup 1.0000x reference)
//
#include <hip/hip_runtime.h>
#include <hip/hip_bf16.h>
#include <math.h>

#define NS 512      // N_way*K_shot support samples
#define NQ 65536    // N_way*Q_query rows
#define DD 1024     // feature dim
#define NW 16       // N_way

// ---------------- row squared-norms (wave per row) ----------------
__global__ void row_norms_kernel(const float* __restrict__ X, float* __restrict__ out, int nrows) {
  int gw = (int)((blockIdx.x * blockDim.x + threadIdx.x) >> 6);
  int lane = threadIdx.x & 63;
  if (gw >= nrows) return;
  const float* row = X + (size_t)gw * DD;
  float s = 0.f;
  #pragma unroll
  for (int i = 0; i < 4; ++i) {
    float4 v = *(const float4*)(row + 4 * lane + 256 * i);
    s += v.x * v.x + v.y * v.y + v.z * v.z + v.w * v.w;
  }
  #pragma unroll
  for (int off = 32; off; off >>= 1) s += __shfl_xor(s, off);
  if (lane == 0) out[gw] = s;
}

// ---------------- Kss = rbf(Zs,Zs) + noise*I  (64x64 tiles) ----------------
__global__ __launch_bounds__(256) void kss_kernel(const float* __restrict__ Zs,
                                                  const float* __restrict__ sn,
                                                  const float* __restrict__ log_ls,
                                                  const float* __restrict__ log_noise,
                                                  float* __restrict__ K) {
  __shared__ __align__(16) float At[16][68];
  __shared__ __align__(16) float Bt[16][68];
  int tid = threadIdx.x;
  int rb = blockIdx.y * 64, cb = blockIdx.x * 64;
  int tx = tid & 15, ty = tid >> 4;
  int srow = tid & 63, skq = (tid >> 6) << 2;
  float acc[4][4] = {};
  for (int kk = 0; kk < DD; kk += 16) {
    __syncthreads();
    float4 a = *(const float4*)(Zs + (size_t)(rb + srow) * DD + kk + skq);
    float4 b = *(const float4*)(Zs + (size_t)(cb + srow) * DD + kk + skq);
    At[skq + 0][srow] = a.x; At[skq + 1][srow] = a.y; At[skq + 2][srow] = a.z; At[skq + 3][srow] = a.w;
    Bt[skq + 0][srow] = b.x; Bt[skq + 1][srow] = b.y; Bt[skq + 2][srow] = b.z; Bt[skq + 3][srow] = b.w;
    __syncthreads();
    #pragma unroll
    for (int k = 0; k < 16; ++k) {
      float4 av = *(const float4*)&At[k][ty * 4];
      float4 bv = *(const float4*)&Bt[k][tx * 4];
      float aa[4] = {av.x, av.y, av.z, av.w};
      float bb[4] = {bv.x, bv.y, bv.z, bv.w};
      #pragma unroll
      for (int i = 0; i < 4; ++i)
        #pragma unroll
        for (int j = 0; j < 4; ++j)
          acc[i][j] = fmaf(aa[i], bb[j], acc[i][j]);
    }
  }
  float inv2 = 0.5f * expf(-2.f * log_ls[0]);
  float noise = expf(2.f * log_noise[0]);
  #pragma unroll
  for (int i = 0; i < 4; ++i)
    #pragma unroll
    for (int j = 0; j < 4; ++j) {
      int r = rb + ty * 4 + i, c = cb + tx * 4 + j;
      float d2 = fmaxf(sn[r] + sn[c] - 2.f * acc[i][j], 0.f);
      float v = expf(-d2 * inv2);
      if (r == c) v += noise;
      K[(size_t)r * NS + c] = v;
    }
}

// ---------------- blocked Cholesky, BS=64 ----------------
__global__ __launch_bounds__(256) void potrf_diag(float* __restrict__ K, int j) {
  __shared__ float A[64][65];
  int tid = threadIdx.x;
  for (int i = tid; i < 64 * 64; i += 256) {
    int r = i >> 6, c = i & 63;
    A[r][c] = K[(size_t)(j + r) * NS + j + c];
  }
  __syncthreads();
  for (int c = 0; c < 64; ++c) {
    if (tid == 0) A[c][c] = sqrtf(A[c][c]);
    __syncthreads();
    float inv = 1.f / A[c][c];
    for (int r = c + 1 + tid; r < 64; r += 256) A[r][c] *= inv;
    __syncthreads();
    int T = 63 - c;
    for (int i = tid; i < T * T; i += 256) {
      int r = c + 1 + i / T, k = c + 1 + i % T;
      if (k <= r) A[r][k] -= A[r][c] * A[k][c];
    }
    __syncthreads();
  }
  for (int i = tid; i < 64 * 64; i += 256) {
    int r = i >> 6, c = i & 63;
    if (c <= r) K[(size_t)(j + r) * NS + j + c] = A[r][c];
  }
}

// rows below panel: solve X * L11^T = A21  (per-row forward substitution)
__global__ __launch_bounds__(256) void trsm_panel(float* __restrict__ K, int j) {
  __shared__ float Ld[64][65];
  int tid = threadIdx.x;
  for (int i = tid; i < 64 * 64; i += 256) {
    int r = i >> 6, c = i & 63;
    Ld[r][c] = K[(size_t)(j + r) * NS + j + c];
  }
  __syncthreads();
  int r = j + 64 + blockIdx.x * 256 + tid;
  if (r >= NS) return;
  float x[64];
  #pragma unroll
  for (int c = 0; c < 64; ++c) {
    float v = K[(size_t)r * NS + j + c];
    #pragma unroll
    for (int k = 0; k < c; ++k) v -= x[k] * Ld[c][k];
    x[c] = v / Ld[c][c];
  }
  #pragma unroll
  for (int c = 0; c < 64; ++c) K[(size_t)r * NS + j + c] = x[c];
}

// trailing update A22 -= L21 * L21^T (64x64 tiles, skip strictly-upper tiles)
__global__ __launch_bounds__(256) void syrk_trailing(float* __restrict__ K, int j) {
  int t0 = j + 64;
  int rbt = t0 + blockIdx.y * 64, cbt = t0 + blockIdx.x * 64;
  if (cbt > rbt) return;
  __shared__ float A[64][69];
  __shared__ float B[64][69];
  int tid = threadIdx.x;
  for (int i = tid; i < 64 * 64; i += 256) {
    int r = i >> 6, k = i & 63;
    A[r][k] = K[(size_t)(rbt + r) * NS + j + k];
    B[r][k] = K[(size_t)(cbt + r) * NS + j + k];
  }
  __syncthreads();
  int tx = tid & 15, ty = tid >> 4;
  float acc[4][4] = {};
  for (int k = 0; k < 64; ++k) {
    float aa[4], bb[4];
    #pragma unroll
    for (int i = 0; i < 4; ++i) aa[i] = A[ty * 4 + i][k];
    #pragma unroll
    for (int i = 0; i < 4; ++i) bb[i] = B[tx * 4 + i][k];
    #pragma unroll
    for (int i = 0; i < 4; ++i)
      #pragma unroll
      for (int jj = 0; jj < 4; ++jj)
        acc[i][jj] = fmaf(aa[i], bb[jj], acc[i][jj]);
  }
  #pragma unroll
  for (int i = 0; i < 4; ++i)
    #pragma unroll
    for (int jj = 0; jj < 4; ++jj)
      K[(size_t)(rbt + ty * 4 + i) * NS + cbt + tx * 4 + jj] -= acc[i][jj];
}

// ---------------- cho_solve: L W = Y1hot, then L^T alpha = W (one WG) ----------------
__global__ __launch_bounds__(256) void cho_solve_kernel(const float* __restrict__ K,
                                                        const int* __restrict__ Ys,
                                                        float* __restrict__ alpha) {
  __shared__ float W[NS][NW];     // 32KB
  __shared__ float Ld[64][65];    // 16.6KB
  __shared__ float invd[64];
  int tid = threadIdx.x;
  for (int i = tid; i < NS * NW; i += 256) {
    int r = i >> 4, n = i & 15;
    W[r][n] = (Ys[r] == n) ? 1.f : 0.f;
  }
  // ---- forward ----
  for (int jb = 0; jb < 8; ++jb) {
    int j = jb << 6;
    __syncthreads();
    for (int i = tid; i < 64 * 64; i += 256) {
      int r = i >> 6, c = i & 63;
      Ld[r][c] = K[(size_t)(j + r) * NS + j + c];
    }
    __syncthreads();
    if (tid < 64) invd[tid] = 1.f / Ld[tid][tid];
    __syncthreads();
    if (tid < 64) {  // wave-lockstep diag solve: lanes = (rq 0..3) x (n 0..15)
      int n = tid & 15, rq = tid >> 4;
      float w[16];
      #pragma unroll
      for (int i = 0; i < 16; ++i) w[i] = W[j + rq + 4 * i][n];
      #pragma unroll
      for (int c = 0; c < 64; ++c) {
        float xc = __shfl(w[c >> 2], ((c & 3) << 4) + n) * invd[c];
        if (rq == (c & 3)) w[c >> 2] = xc;
        #pragma unroll
        for (int i = 0; i < 16; ++i) {
          int r = rq + 4 * i;
          if (r > c) w[i] -= Ld[r][c] * xc;
        }
      }
      #pragma unroll
      for (int i = 0; i < 16; ++i) W[j + rq + 4 * i][n] = w[i];
    }
    __syncthreads();
    int rows = NS - j - 64;
    for (int i = tid; i < rows * NW; i += 256) {
      int r = j + 64 + (i >> 4), n = i & 15;
      float s = W[r][n];
      #pragma unroll 8
      for (int c = 0; c < 64; ++c) s -= K[(size_t)r * NS + j + c] * W[j + c][n];
      W[r][n] = s;
    }
  }
  // ---- backward ----
  for (int jb = 7; jb >= 0; --jb) {
    int j = jb << 6;
    __syncthreads();
    for (int i = tid; i < 64 * 64; i += 256) {
      int r = i >> 6, c = i & 63;
      Ld[r][c] = K[(size_t)(j + r) * NS + j + c];
    }
    __syncthreads();
    if (tid < 64) invd[tid] = 1.f / Ld[tid][tid];
    __syncthreads();
    if (tid < 64) {
      int n = tid & 15, rq = tid >> 4;
      float w[16];
      #pragma unroll
      for (int i = 0; i < 16; ++i) w[i] = W[j + rq + 4 * i][n];
      #pragma unroll
      for (int c = 63; c >= 0; --c) {
        float xc = __shfl(w[c >> 2], ((c & 3) << 4) + n) * invd[c];
        if (rq == (c & 3)) w[c >> 2] = xc;
        #pragma unroll
        for (int i = 0; i < 16; ++i) {
          int r = rq + 4 * i;
          if (r < c) w[i] -= Ld[c][r] * xc;
        }
      }
      #pragma unroll
      for (int i = 0; i < 16; ++i) W[j + rq + 4 * i][n] = w[i];
    }
    __syncthreads();
    for (int i = tid; i < j * NW; i += 256) {  // rows above
      int r = i >> 4, n = i & 15;
      float s = W[r][n];
      #pragma unroll 8
      for (int c = 0; c < 64; ++c) s -= K[(size_t)(j + c) * NS + r] * W[j + c][n];
      W[r][n] = s;
    }
  }
  __syncthreads();
  for (int i = tid; i < NS * NW; i += 256) alpha[i] = W[i >> 4][i & 15];
}

// ---------------- fused: Kqs tile -> f += Kqs*alpha -> softmax ----------------
__global__ __launch_bounds__(512) void fused_fq(const float* __restrict__ Zq,
                                                const float* __restrict__ Zs,
                                                const float* __restrict__ qn,
                                                const float* __restrict__ sn,
                                                const float* __restrict__ alpha,
                                                const float* __restrict__ log_ls,
                                                float* __restrict__ out) {
  __shared__ __align__(16) float Qt[16][140];
  __shared__ __align__(16) float St[16][140];
  __shared__ __align__(16) float Al[128][16];
  __shared__ float fl[128][16];
  __shared__ float snl[128];
  __shared__ float qnl[128];

  int tid = threadIdx.x;
  int rb = blockIdx.x * 128;
  int rg = tid >> 4;   // 0..31 -> rows rg*4..+4
  int cg = tid & 15;   // 0..15 -> cols cg*8..+8
  for (int i = tid; i < 128 * 16; i += 512) fl[i >> 4][i & 15] = 0.f;
  if (tid < 128) qnl[tid] = qn[rb + tid];
  float inv2 = 0.5f * expf(-2.f * log_ls[0]);
  int srow = tid >> 2, skq = (tid & 3) << 2;

  for (int cc = 0; cc < NS; cc += 128) {
    __syncthreads();
    {
      int c = tid >> 2, nq = (tid & 3) << 2;
      *(float4*)&Al[c][nq] = *(const float4*)(alpha + (size_t)(cc + c) * NW + nq);
      if (tid < 128) snl[tid] = sn[cc + tid];
    }
    float acc[4][8] = {};
    for (int kk = 0; kk < DD; kk += 16) {
      __syncthreads();
      float4 q = *(const float4*)(Zq + (size_t)(rb + srow) * DD + kk + skq);
      float4 s = *(const float4*)(Zs + (size_t)(cc + srow) * DD + kk + skq);
      Qt[skq + 0][srow] = q.x; Qt[skq + 1][srow] = q.y; Qt[skq + 2][srow] = q.z; Qt[skq + 3][srow] = q.w;
      St[skq + 0][srow] = s.x; St[skq + 1][srow] = s.y; St[skq + 2][srow] = s.z; St[skq + 3][srow] = s.w;
      __syncthreads();
      #pragma unroll
      for (int k = 0; k < 16; ++k) {
        float4 a  = *(const float4*)&Qt[k][rg * 4];
        float4 b0 = *(const float4*)&St[k][cg * 8];
        float4 b1 = *(const float4*)&St[k][cg * 8 + 4];
        float av[4] = {a.x, a.y, a.z, a.w};
        float bv[8] = {b0.x, b0.y, b0.z, b0.w, b1.x, b1.y, b1.z, b1.w};
        #pragma unroll
        for (int ri = 0; ri < 4; ++ri)
          #pragma unroll
          for (int cj = 0; cj < 8; ++cj)
            acc[ri][cj] = fmaf(av[ri], bv[cj], acc[ri][cj]);
      }
    }
    // epilogue: kq = exp(-d2/(2 ls^2)); fpart = kq @ alpha_chunk
    float fp[4][16] = {};
    #pragma unroll
    for (int j8 = 0; j8 < 8; ++j8) {
      int c = cg * 8 + j8;
      float snc = snl[c];
      #pragma unroll
      for (int ri = 0; ri < 4; ++ri) {
        float d2 = fmaxf(qnl[rg * 4 + ri] + snc - 2.f * acc[ri][j8], 0.f);
        float kq = __expf(-d2 * inv2);
        #pragma unroll
        for (int n = 0; n < NW; ++n) fp[ri][n] = fmaf(kq, Al[c][n], fp[ri][n]);
      }
    }
    #pragma unroll
    for (int m = 1; m < 16; m <<= 1)
      #pragma unroll
      for (int ri = 0; ri < 4; ++ri)
        #pragma unroll
        for (int n = 0; n < NW; ++n)
          fp[ri][n] += __shfl_xor(fp[ri][n], m);
    if (cg == 0) {
      #pragma unroll
      for (int ri = 0; ri < 4; ++ri)
        #pragma unroll
        for (int n = 0; n < NW; ++n)
          fl[rg * 4 + ri][n] += fp[ri][n];
    }
  }
  __syncthreads();
  if (tid < 128) {
    int r = tid;
    float m = fl[r][0];
    #pragma unroll
    for (int n = 1; n < NW; ++n) m = fmaxf(m, fl[r][n]);
    float e[NW], ssum = 0.f;
    #pragma unroll
    for (int n = 0; n < NW; ++n) { e[n] = __expf(fl[r][n] - m); ssum += e[n]; }
    float inv = 1.f / ssum;
    #pragma unroll
    for (int n = 0; n < NW; ++n) out[(size_t)(rb + r) * NW + n] = e[n] * inv;
  }
}

extern "C" void kernel_launch(void* const* d_in, const int* in_sizes, int n_in,
                              void* d_out, int out_size, void* d_ws, size_t ws_size,
                              hipStream_t stream) {
  (void)in_sizes; (void)n_in; (void)out_size; (void)ws_size;
  const float* Zs = (const float*)d_in[0];
  const int*   Ys = (const int*)d_in[1];
  const float* Zq = (const float*)d_in[2];
  const float* log_ls = (const float*)d_in[3];
  const float* log_noise = (const float*)d_in[4];
  float* out = (float*)d_out;

  float* ws = (float*)d_ws;
  float* sn = ws;                       // 512
  float* qn = sn + NS;                  // 65536
  float* K  = qn + NQ;                  // 512*512
  float* alpha = K + (size_t)NS * NS;   // 512*16

  row_norms_kernel<<<(NS * 64) / 256, 256, 0, stream>>>(Zs, sn, NS);
  row_norms_kernel<<<(NQ * 64) / 256, 256, 0, stream>>>(Zq, qn, NQ);
  kss_kernel<<<dim3(8, 8), 256, 0, stream>>>(Zs, sn, log_ls, log_noise, K);
  for (int j = 0; j < NS; j += 64) {
    potrf_diag<<<1, 256, 0, stream>>>(K, j);
    int rows = NS - j - 64;
    if (rows > 0) {
      trsm_panel<<<(rows + 255) / 256, 256, 0, stream>>>(K, j);
      int t = rows / 64;
      syrk_trailing<<<dim3(t, t), 256, 0, stream>>>(K, j);
    }
  }
  cho_solve_kernel<<<1, 256, 0, stream>>>(K, Ys, alpha);
  fused_fq<<<NQ / 128, 512, 0, stream>>>(Zq, Zs, qn, sn, alpha, log_ls, out);
}

// Round 2
// 1936.514 us; speedup vs baseline: 1.4487x; 1.4487x over previous
//
#include <hip/hip_runtime.h>
#include <math.h>

#define NS 512      // N_way*K_shot support samples
#define NQ 65536    // N_way*Q_query rows
#define DD 1024     // feature dim
#define NW 16       // N_way

typedef __attribute__((ext_vector_type(8))) short short8x;
typedef __attribute__((ext_vector_type(4))) float floatx4;

static __device__ __forceinline__ unsigned short bf_trunc(float x) {
  return (unsigned short)(__float_as_uint(x) >> 16);
}
static __device__ __forceinline__ float bf_tof(unsigned short h) {
  return __uint_as_float(((unsigned)h) << 16);
}
static __device__ __forceinline__ unsigned short bf_rne(float x) {
  unsigned u = __float_as_uint(x);
  return (unsigned short)((u + 0x7FFFu + ((u >> 16) & 1u)) >> 16);
}

// split f32 -> (hi, lo) bf16 pair, swizzled 8B LDS store. k0 multiple of 4.
#define STASH(Hp, Lp, row, k0, v) do {                                      \
    unsigned e_ = (unsigned)((((row) * 32 + (k0)) ^ (((row) & 7) << 3)));   \
    ushort4 h_, l_;                                                         \
    h_.x = bf_trunc((v).x); l_.x = bf_trunc((v).x - bf_tof(h_.x));          \
    h_.y = bf_trunc((v).y); l_.y = bf_trunc((v).y - bf_tof(h_.y));          \
    h_.z = bf_trunc((v).z); l_.z = bf_trunc((v).z - bf_tof(h_.z));          \
    h_.w = bf_trunc((v).w); l_.w = bf_trunc((v).w - bf_tof(h_.w));          \
    *(ushort4*)&Hp[e_] = h_; *(ushort4*)&Lp[e_] = l_;                       \
  } while (0)

// ---------------- row squared-norms (wave per row) — Zs only ----------------
__global__ void row_norms_kernel(const float* __restrict__ X, float* __restrict__ out, int nrows) {
  int gw = (int)((blockIdx.x * blockDim.x + threadIdx.x) >> 6);
  int lane = threadIdx.x & 63;
  if (gw >= nrows) return;
  const float* row = X + (size_t)gw * DD;
  float s = 0.f;
  #pragma unroll
  for (int i = 0; i < 4; ++i) {
    float4 v = *(const float4*)(row + 4 * lane + 256 * i);
    s += v.x * v.x + v.y * v.y + v.z * v.z + v.w * v.w;
  }
  #pragma unroll
  for (int off = 32; off; off >>= 1) s += __shfl_xor(s, off);
  if (lane == 0) out[gw] = s;
}

// ---------------- Kss = rbf(Zs,Zs) + noise*I  (64x64 tiles, fp32 exact) ----------------
__global__ __launch_bounds__(256) void kss_kernel(const float* __restrict__ Zs,
                                                  const float* __restrict__ sn,
                                                  const float* __restrict__ log_ls,
                                                  const float* __restrict__ log_noise,
                                                  float* __restrict__ K) {
  __shared__ __align__(16) float At[16][68];
  __shared__ __align__(16) float Bt[16][68];
  int tid = threadIdx.x;
  int rb = blockIdx.y * 64, cb = blockIdx.x * 64;
  int tx = tid & 15, ty = tid >> 4;
  int srow = tid & 63, skq = (tid >> 6) << 2;
  float acc[4][4] = {};
  for (int kk = 0; kk < DD; kk += 16) {
    __syncthreads();
    float4 a = *(const float4*)(Zs + (size_t)(rb + srow) * DD + kk + skq);
    float4 b = *(const float4*)(Zs + (size_t)(cb + srow) * DD + kk + skq);
    At[skq + 0][srow] = a.x; At[skq + 1][srow] = a.y; At[skq + 2][srow] = a.z; At[skq + 3][srow] = a.w;
    Bt[skq + 0][srow] = b.x; Bt[skq + 1][srow] = b.y; Bt[skq + 2][srow] = b.z; Bt[skq + 3][srow] = b.w;
    __syncthreads();
    #pragma unroll
    for (int k = 0; k < 16; ++k) {
      float4 av = *(const float4*)&At[k][ty * 4];
      float4 bv = *(const float4*)&Bt[k][tx * 4];
      float aa[4] = {av.x, av.y, av.z, av.w};
      float bb[4] = {bv.x, bv.y, bv.z, bv.w};
      #pragma unroll
      for (int i = 0; i < 4; ++i)
        #pragma unroll
        for (int j = 0; j < 4; ++j)
          acc[i][j] = fmaf(aa[i], bb[j], acc[i][j]);
    }
  }
  float inv2 = 0.5f * expf(-2.f * log_ls[0]);
  float noise = expf(2.f * log_noise[0]);
  #pragma unroll
  for (int i = 0; i < 4; ++i)
    #pragma unroll
    for (int j = 0; j < 4; ++j) {
      int r = rb + ty * 4 + i, c = cb + tx * 4 + j;
      float d2 = fmaxf(sn[r] + sn[c] - 2.f * acc[i][j], 0.f);
      float v = expf(-d2 * inv2);
      if (r == c) v += noise;
      K[(size_t)r * NS + c] = v;
    }
}

// ---------------- fused panel: potrf(64x64 diag) + trsm(rows below) ----------------
__global__ __launch_bounds__(256) void chol_panel(float* __restrict__ K, int j) {
  __shared__ float A[64][65];
  int tid = threadIdx.x;
  for (int i = tid; i < 4096; i += 256) {
    int r = i >> 6, c = i & 63;
    A[r][c] = K[(size_t)(j + r) * NS + j + c];
  }
  __syncthreads();
  for (int c = 0; c < 64; ++c) {
    if (tid == 0) A[c][c] = sqrtf(A[c][c]);
    __syncthreads();
    float inv = 1.f / A[c][c];
    if (tid > c && tid < 64) A[tid][c] *= inv;
    __syncthreads();
    // full-rectangle rank-1 update (upper junk never read)
    for (int i = tid; i < 4096; i += 256) {
      int r = i >> 6, k = i & 63;
      if (r > c && k > c) A[r][k] -= A[r][c] * A[k][c];
    }
    __syncthreads();
  }
  for (int i = tid; i < 4096; i += 256) {
    int r = i >> 6, c = i & 63;
    if (c <= r) K[(size_t)(j + r) * NS + j + c] = A[r][c];
  }
  // trsm: rows below panel solve X * L11^T = A21
  for (int r0 = j + 64 + tid; r0 < NS; r0 += 256) {
    float x[64];
    #pragma unroll
    for (int c = 0; c < 64; ++c) {
      float v = K[(size_t)r0 * NS + j + c];
      #pragma unroll
      for (int k = 0; k < c; ++k) v -= x[k] * A[c][k];
      x[c] = v / A[c][c];
    }
    #pragma unroll
    for (int c = 0; c < 64; ++c) K[(size_t)r0 * NS + j + c] = x[c];
  }
}

// trailing update A22 -= L21 * L21^T (64x64 tiles, skip strictly-upper tiles)
__global__ __launch_bounds__(256) void syrk_trailing(float* __restrict__ K, int j) {
  int t0 = j + 64;
  int rbt = t0 + blockIdx.y * 64, cbt = t0 + blockIdx.x * 64;
  if (cbt > rbt) return;
  __shared__ float A[64][69];
  __shared__ float B[64][69];
  int tid = threadIdx.x;
  for (int i = tid; i < 64 * 64; i += 256) {
    int r = i >> 6, k = i & 63;
    A[r][k] = K[(size_t)(rbt + r) * NS + j + k];
    B[r][k] = K[(size_t)(cbt + r) * NS + j + k];
  }
  __syncthreads();
  int tx = tid & 15, ty = tid >> 4;
  float acc[4][4] = {};
  for (int k = 0; k < 64; ++k) {
    float aa[4], bb[4];
    #pragma unroll
    for (int i = 0; i < 4; ++i) aa[i] = A[ty * 4 + i][k];
    #pragma unroll
    for (int i = 0; i < 4; ++i) bb[i] = B[tx * 4 + i][k];
    #pragma unroll
    for (int i = 0; i < 4; ++i)
      #pragma unroll
      for (int jj = 0; jj < 4; ++jj)
        acc[i][jj] = fmaf(aa[i], bb[jj], acc[i][jj]);
  }
  #pragma unroll
  for (int i = 0; i < 4; ++i)
    #pragma unroll
    for (int jj = 0; jj < 4; ++jj)
      K[(size_t)(rbt + ty * 4 + i) * NS + cbt + tx * 4 + jj] -= acc[i][jj];
}

// ---------------- cho_solve: L W = Y1hot, then L^T alpha = W; emit alpha^T bf16 ----------------
__global__ __launch_bounds__(1024) void cho_solve_kernel(const float* __restrict__ K,
                                                         const int* __restrict__ Ys,
                                                         unsigned short* __restrict__ alpha_t) {
  __shared__ float W[NS][NW];
  __shared__ float Ld[64][65];
  __shared__ float invd[64];
  int tid = threadIdx.x;
  for (int i = tid; i < NS * NW; i += 1024) {
    int r = i >> 4, n = i & 15;
    W[r][n] = (Ys[r] == n) ? 1.f : 0.f;
  }
  // ---- forward ----
  for (int jb = 0; jb < 8; ++jb) {
    int j = jb << 6;
    __syncthreads();
    for (int i = tid; i < 64 * 64; i += 1024) {
      int r = i >> 6, c = i & 63;
      Ld[r][c] = K[(size_t)(j + r) * NS + j + c];
    }
    __syncthreads();
    if (tid < 64) invd[tid] = 1.f / Ld[tid][tid];
    __syncthreads();
    if (tid < 64) {  // wave-lockstep diag solve
      int n = tid & 15, rq = tid >> 4;
      float w[16];
      #pragma unroll
      for (int i = 0; i < 16; ++i) w[i] = W[j + rq + 4 * i][n];
      #pragma unroll
      for (int c = 0; c < 64; ++c) {
        float xc = __shfl(w[c >> 2], ((c & 3) << 4) + n) * invd[c];
        if (rq == (c & 3)) w[c >> 2] = xc;
        #pragma unroll
        for (int i = 0; i < 16; ++i) {
          int r = rq + 4 * i;
          if (r > c) w[i] -= Ld[r][c] * xc;
        }
      }
      #pragma unroll
      for (int i = 0; i < 16; ++i) W[j + rq + 4 * i][n] = w[i];
    }
    __syncthreads();
    int rows = NS - j - 64;
    for (int i = tid; i < rows * NW; i += 1024) {
      int r = j + 64 + (i >> 4), n = i & 15;
      float s = W[r][n];
      #pragma unroll 8
      for (int c = 0; c < 64; ++c) s -= K[(size_t)r * NS + j + c] * W[j + c][n];
      W[r][n] = s;
    }
  }
  // ---- backward ----
  for (int jb = 7; jb >= 0; --jb) {
    int j = jb << 6;
    __syncthreads();
    for (int i = tid; i < 64 * 64; i += 1024) {
      int r = i >> 6, c = i & 63;
      Ld[r][c] = K[(size_t)(j + r) * NS + j + c];
    }
    __syncthreads();
    if (tid < 64) invd[tid] = 1.f / Ld[tid][tid];
    __syncthreads();
    if (tid < 64) {
      int n = tid & 15, rq = tid >> 4;
      float w[16];
      #pragma unroll
      for (int i = 0; i < 16; ++i) w[i] = W[j + rq + 4 * i][n];
      #pragma unroll
      for (int c = 63; c >= 0; --c) {
        float xc = __shfl(w[c >> 2], ((c & 3) << 4) + n) * invd[c];
        if (rq == (c & 3)) w[c >> 2] = xc;
        #pragma unroll
        for (int i = 0; i < 16; ++i) {
          int r = rq + 4 * i;
          if (r < c) w[i] -= Ld[c][r] * xc;
        }
      }
      #pragma unroll
      for (int i = 0; i < 16; ++i) W[j + rq + 4 * i][n] = w[i];
    }
    __syncthreads();
    for (int i = tid; i < j * NW; i += 1024) {
      int r = i >> 4, n = i & 15;
      float s = W[r][n];
      #pragma unroll 8
      for (int c = 0; c < 64; ++c) s -= K[(size_t)(j + c) * NS + r] * W[j + c][n];
      W[r][n] = s;
    }
  }
  __syncthreads();
  for (int i = tid; i < NS * NW; i += 1024) {
    int r = i >> 4, n = i & 15;
    alpha_t[n * NS + r] = bf_rne(W[r][n]);
  }
}

// ---------------- fused: split-bf16 MFMA Gram -> exp -> MFMA PV -> softmax ----------------
__global__ __launch_bounds__(512) void fused_v2(const float* __restrict__ Zq,
                                                const float* __restrict__ Zs,
                                                const float* __restrict__ sn,
                                                const unsigned short* __restrict__ alpha_t,
                                                const float* __restrict__ log_ls,
                                                float* __restrict__ out) {
  __shared__ __align__(16) unsigned short LB[32768];  // 64 KB, unioned
  __shared__ float qnl[128];
  __shared__ float snl[256];
  unsigned short* AhB = LB;            // Zq hi  [128][32]
  unsigned short* AlB = LB + 4096;     // Zq lo
  unsigned short* BhB = LB + 8192;     // Zs hi  [256][32]
  unsigned short* BlB = LB + 16384;    // Zs lo
  unsigned short* KqB = LB;            // Kq bf16 [128][256] (epilogue overlay)

  const int tid = threadIdx.x;
  const int lane = tid & 63;
  const int w = tid >> 6;              // 8 waves: 2(m) x 4(n)
  const int wm = w >> 2, wn = w & 3;
  const int l15 = lane & 15, l4 = lane >> 4;
  const int rb = blockIdx.x * 128;
  const float inv2 = 0.5f * __expf(-2.f * log_ls[0]);
  const unsigned swz = (unsigned)((l15 & 7) << 3);

  if (tid < 128) qnl[tid] = 0.f;
  __syncthreads();

  const int qrow0 = tid >> 3;          // 0..63
  const int qk0 = (tid & 7) * 4;
  const int qrow1 = 64 + qrow0;

  floatx4 facc = {0.f, 0.f, 0.f, 0.f};

  for (int cc = 0; cc < NS; cc += 256) {
    if (tid < 256) snl[tid] = sn[cc + tid];
    floatx4 acc[4][4];
    #pragma unroll
    for (int a = 0; a < 4; ++a)
      #pragma unroll
      for (int b = 0; b < 4; ++b) acc[a][b] = (floatx4){0.f, 0.f, 0.f, 0.f};

    // prefetch kt = 0
    float4 pq0 = *(const float4*)(Zq + (size_t)(rb + qrow0) * DD + qk0);
    float4 pq1 = *(const float4*)(Zq + (size_t)(rb + qrow1) * DD + qk0);
    float4 ps[4];
    #pragma unroll
    for (int u = 0; u < 4; ++u) {
      int idx = tid + (u << 9);
      ps[u] = *(const float4*)(Zs + (size_t)(cc + (idx >> 3)) * DD + ((idx & 7) * 4));
    }

    for (int kt = 0; kt < 32; ++kt) {
      // ---- STORE phase: regs -> swizzled split-bf16 LDS ----
      STASH(AhB, AlB, qrow0, qk0, pq0);
      STASH(AhB, AlB, qrow1, qk0, pq1);
      #pragma unroll
      for (int u = 0; u < 4; ++u) {
        int idx = tid + (u << 9);
        int srow = idx >> 3, sk0 = (idx & 7) * 4;
        STASH(BhB, BlB, srow, sk0, ps[u]);
      }
      if (cc == 0) {  // fold Zq row-norm accumulation into chunk-0 staging
        float s0 = pq0.x * pq0.x + pq0.y * pq0.y + pq0.z * pq0.z + pq0.w * pq0.w;
        float s1 = pq1.x * pq1.x + pq1.y * pq1.y + pq1.z * pq1.z + pq1.w * pq1.w;
        #pragma unroll
        for (int d = 1; d < 8; d <<= 1) { s0 += __shfl_xor(s0, d); s1 += __shfl_xor(s1, d); }
        if ((tid & 7) == 0) { qnl[qrow0] += s0; qnl[qrow1] += s1; }
      }
      __syncthreads();
      // ---- prefetch next iter (hidden under MFMA) ----
      if (kt < 31) {
        int kk2 = (kt + 1) << 5;
        pq0 = *(const float4*)(Zq + (size_t)(rb + qrow0) * DD + kk2 + qk0);
        pq1 = *(const float4*)(Zq + (size_t)(rb + qrow1) * DD + kk2 + qk0);
        #pragma unroll
        for (int u = 0; u < 4; ++u) {
          int idx = tid + (u << 9);
          ps[u] = *(const float4*)(Zs + (size_t)(cc + (idx >> 3)) * DD + kk2 + ((idx & 7) * 4));
        }
      }
      // ---- compute: 16 ds_read_b128 + 48 MFMA ----
      short8x ah[4], al[4], bh[4], bl[4];
      #pragma unroll
      for (int mi = 0; mi < 4; ++mi) {
        unsigned e = (unsigned)((wm * 64 + mi * 16 + l15) * 32 + 8 * l4) ^ swz;
        ah[mi] = *(const short8x*)&AhB[e];
        al[mi] = *(const short8x*)&AlB[e];
      }
      #pragma unroll
      for (int ni = 0; ni < 4; ++ni) {
        unsigned e = (unsigned)((wn * 64 + ni * 16 + l15) * 32 + 8 * l4) ^ swz;
        bh[ni] = *(const short8x*)&BhB[e];
        bl[ni] = *(const short8x*)&BlB[e];
      }
      #pragma unroll
      for (int mi = 0; mi < 4; ++mi)
        #pragma unroll
        for (int ni = 0; ni < 4; ++ni) {
          acc[mi][ni] = __builtin_amdgcn_mfma_f32_16x16x32_bf16(ah[mi], bh[ni], acc[mi][ni], 0, 0, 0);
          acc[mi][ni] = __builtin_amdgcn_mfma_f32_16x16x32_bf16(ah[mi], bl[ni], acc[mi][ni], 0, 0, 0);
          acc[mi][ni] = __builtin_amdgcn_mfma_f32_16x16x32_bf16(al[mi], bh[ni], acc[mi][ni], 0, 0, 0);
        }
      __syncthreads();
    }

    // ---- epilogue: PV B-frags (alpha^T, global/L2), kq -> KqB, PV MFMA ----
    short8x bfr[8];
    #pragma unroll
    for (int s = 0; s < 8; ++s)
      bfr[s] = *(const short8x*)(alpha_t + ((size_t)l15 * NS + cc + 32 * s + 8 * l4));

    #pragma unroll
    for (int mi = 0; mi < 4; ++mi)
      #pragma unroll
      for (int rr = 0; rr < 4; ++rr) {
        int row_l = wm * 64 + mi * 16 + l4 * 4 + rr;
        float qv = qnl[row_l];
        unsigned sw = (unsigned)((row_l & 7) << 3);
        #pragma unroll
        for (int ni = 0; ni < 4; ++ni) {
          int col = wn * 64 + ni * 16 + l15;
          float d2 = fmaxf(qv + snl[col] - 2.f * acc[mi][ni][rr], 0.f);
          float kq = __expf(-d2 * inv2);
          KqB[(unsigned)(row_l * 256 + col) ^ sw] = bf_rne(kq);
        }
      }
    __syncthreads();
    #pragma unroll
    for (int s = 0; s < 8; ++s) {
      unsigned e = (unsigned)((w * 16 + l15) * 256 + 32 * s + 8 * l4) ^ swz;
      short8x ak = *(const short8x*)&KqB[e];
      facc = __builtin_amdgcn_mfma_f32_16x16x32_bf16(ak, bfr[s], facc, 0, 0, 0);
    }
    __syncthreads();
  }

  // ---- softmax over 16 classes (spread across 16-lane groups) ----
  #pragma unroll
  for (int r = 0; r < 4; ++r) {
    float v = facc[r];
    float m = v;
    #pragma unroll
    for (int d = 1; d < 16; d <<= 1) m = fmaxf(m, __shfl_xor(m, d));
    float e = __expf(v - m);
    float s = e;
    #pragma unroll
    for (int d = 1; d < 16; d <<= 1) s += __shfl_xor(s, d);
    out[(size_t)(rb + w * 16 + l4 * 4 + r) * NW + l15] = e / s;
  }
}

extern "C" void kernel_launch(void* const* d_in, const int* in_sizes, int n_in,
                              void* d_out, int out_size, void* d_ws, size_t ws_size,
                              hipStream_t stream) {
  (void)in_sizes; (void)n_in; (void)out_size; (void)ws_size;
  const float* Zs = (const float*)d_in[0];
  const int*   Ys = (const int*)d_in[1];
  const float* Zq = (const float*)d_in[2];
  const float* log_ls = (const float*)d_in[3];
  const float* log_noise = (const float*)d_in[4];
  float* out = (float*)d_out;

  float* ws = (float*)d_ws;
  float* K  = ws;                                   // 512*512 f32
  float* sn = ws + (size_t)NS * NS;                 // 512 f32
  unsigned short* alpha_t = (unsigned short*)(sn + NS);  // [16][512] bf16

  row_norms_kernel<<<128, 256, 0, stream>>>(Zs, sn, NS);
  kss_kernel<<<dim3(8, 8), 256, 0, stream>>>(Zs, sn, log_ls, log_noise, K);
  for (int j = 0; j < NS; j += 64) {
    chol_panel<<<1, 256, 0, stream>>>(K, j);
    int rows = NS - j - 64;
    if (rows > 0) {
      int t = rows / 64;
      syrk_trailing<<<dim3(t, t), 256, 0, stream>>>(K, j);
    }
  }
  cho_solve_kernel<<<1, 1024, 0, stream>>>(K, Ys, alpha_t);
  fused_v2<<<NQ / 128, 512, 0, stream>>>(Zq, Zs, sn, alpha_t, log_ls, out);
}

// Round 3
// 1654.339 us; speedup vs baseline: 1.6958x; 1.1706x over previous
//
#include <hip/hip_runtime.h>
#include <math.h>

#define NS 512      // N_way*K_shot support samples
#define NQ 65536    // N_way*Q_query rows
#define DD 1024     // feature dim
#define NW 16       // N_way

typedef __attribute__((ext_vector_type(8))) short short8x;
typedef __attribute__((ext_vector_type(4))) float floatx4;

static __device__ __forceinline__ unsigned short bf_trunc(float x) {
  return (unsigned short)(__float_as_uint(x) >> 16);
}
static __device__ __forceinline__ float bf_tof(unsigned short h) {
  return __uint_as_float(((unsigned)h) << 16);
}
static __device__ __forceinline__ unsigned short bf_rne(float x) {
  unsigned u = __float_as_uint(x);
  return (unsigned short)((u + 0x7FFFu + ((u >> 16) & 1u)) >> 16);
}

// split f32 -> (hi, lo) bf16 pair, swizzled 8B LDS store. k0 multiple of 4.
#define STASH(Hp, Lp, row, k0, v) do {                                      \
    unsigned e_ = (unsigned)((((row) * 32 + (k0)) ^ (((row) & 7) << 3)));   \
    ushort4 h_, l_;                                                         \
    h_.x = bf_trunc((v).x); l_.x = bf_trunc((v).x - bf_tof(h_.x));          \
    h_.y = bf_trunc((v).y); l_.y = bf_trunc((v).y - bf_tof(h_.y));          \
    h_.z = bf_trunc((v).z); l_.z = bf_trunc((v).z - bf_tof(h_.z));          \
    h_.w = bf_trunc((v).w); l_.w = bf_trunc((v).w - bf_tof(h_.w));          \
    *(ushort4*)&Hp[e_] = h_; *(ushort4*)&Lp[e_] = l_;                       \
  } while (0)

// ---------------- row squared-norms (wave per row) — Zs only ----------------
__global__ void row_norms_kernel(const float* __restrict__ X, float* __restrict__ out, int nrows) {
  int gw = (int)((blockIdx.x * blockDim.x + threadIdx.x) >> 6);
  int lane = threadIdx.x & 63;
  if (gw >= nrows) return;
  const float* row = X + (size_t)gw * DD;
  float s = 0.f;
  #pragma unroll
  for (int i = 0; i < 4; ++i) {
    float4 v = *(const float4*)(row + 4 * lane + 256 * i);
    s += v.x * v.x + v.y * v.y + v.z * v.z + v.w * v.w;
  }
  #pragma unroll
  for (int off = 32; off; off >>= 1) s += __shfl_xor(s, off);
  if (lane == 0) out[gw] = s;
}

// ---------------- Kss = rbf(Zs,Zs) + noise*I  (64x64 tiles, fp32 exact) ----------------
__global__ __launch_bounds__(256) void kss_kernel(const float* __restrict__ Zs,
                                                  const float* __restrict__ sn,
                                                  const float* __restrict__ log_ls,
                                                  const float* __restrict__ log_noise,
                                                  float* __restrict__ K) {
  __shared__ __align__(16) float At[16][68];
  __shared__ __align__(16) float Bt[16][68];
  int tid = threadIdx.x;
  int rb = blockIdx.y * 64, cb = blockIdx.x * 64;
  int tx = tid & 15, ty = tid >> 4;
  int srow = tid & 63, skq = (tid >> 6) << 2;
  float acc[4][4] = {};
  for (int kk = 0; kk < DD; kk += 16) {
    __syncthreads();
    float4 a = *(const float4*)(Zs + (size_t)(rb + srow) * DD + kk + skq);
    float4 b = *(const float4*)(Zs + (size_t)(cb + srow) * DD + kk + skq);
    At[skq + 0][srow] = a.x; At[skq + 1][srow] = a.y; At[skq + 2][srow] = a.z; At[skq + 3][srow] = a.w;
    Bt[skq + 0][srow] = b.x; Bt[skq + 1][srow] = b.y; Bt[skq + 2][srow] = b.z; Bt[skq + 3][srow] = b.w;
    __syncthreads();
    #pragma unroll
    for (int k = 0; k < 16; ++k) {
      float4 av = *(const float4*)&At[k][ty * 4];
      float4 bv = *(const float4*)&Bt[k][tx * 4];
      float aa[4] = {av.x, av.y, av.z, av.w};
      float bb[4] = {bv.x, bv.y, bv.z, bv.w};
      #pragma unroll
      for (int i = 0; i < 4; ++i)
        #pragma unroll
        for (int j = 0; j < 4; ++j)
          acc[i][j] = fmaf(aa[i], bb[j], acc[i][j]);
    }
  }
  float inv2 = 0.5f * expf(-2.f * log_ls[0]);
  float noise = expf(2.f * log_noise[0]);
  #pragma unroll
  for (int i = 0; i < 4; ++i)
    #pragma unroll
    for (int j = 0; j < 4; ++j) {
      int r = rb + ty * 4 + i, c = cb + tx * 4 + j;
      float d2 = fmaxf(sn[r] + sn[c] - 2.f * acc[i][j], 0.f);
      float v = expf(-d2 * inv2);
      if (r == c) v += noise;
      K[(size_t)r * NS + c] = v;
    }
}

// ---------------- fused panel: potrf(64x64 diag) + trsm(rows below) ----------------
// diag kept in side arrays (diag/idia) so A[c][c] is never overwritten ->
// 2 barriers per column instead of 3, no read/write race.
__global__ __launch_bounds__(512) void chol_panel(float* __restrict__ K, int j) {
  __shared__ float A[64][65];
  __shared__ float diag[64], idia[64];
  int tid = threadIdx.x;
  for (int i = tid; i < 4096; i += 512) {
    int r = i >> 6, c = i & 63;
    A[r][c] = K[(size_t)(j + r) * NS + j + c];
  }
  __syncthreads();
  for (int c = 0; c < 64; ++c) {
    float d = A[c][c];               // stable: diagonal never written in-place
    float s = sqrtf(d);
    float inv = 1.f / s;
    if (tid == c) { diag[c] = s; idia[c] = inv; }
    if (tid < 64 && tid > c) A[tid][c] *= inv;
    __syncthreads();
    for (int i = tid; i < 4096; i += 512) {
      int r = i >> 6, k = i & 63;
      if (r > c && k > c) A[r][k] -= A[r][c] * A[k][c];
    }
    __syncthreads();
  }
  for (int i = tid; i < 4096; i += 512) {
    int r = i >> 6, c = i & 63;
    if (c <= r) K[(size_t)(j + r) * NS + j + c] = (c == r) ? diag[r] : A[r][c];
  }
  // trsm: rows below panel solve X * L11^T = A21 (one row per thread)
  for (int r0 = j + 64 + tid; r0 < NS; r0 += 512) {
    float x[64];
    #pragma unroll
    for (int c = 0; c < 64; ++c) {
      float v = K[(size_t)r0 * NS + j + c];
      #pragma unroll
      for (int k = 0; k < c; ++k) v -= x[k] * A[c][k];
      x[c] = v * idia[c];
    }
    #pragma unroll
    for (int c = 0; c < 64; ++c) K[(size_t)r0 * NS + j + c] = x[c];
  }
}

// trailing update A22 -= L21 * L21^T (64x64 tiles, skip strictly-upper tiles)
__global__ __launch_bounds__(256) void syrk_trailing(float* __restrict__ K, int j) {
  int t0 = j + 64;
  int rbt = t0 + blockIdx.y * 64, cbt = t0 + blockIdx.x * 64;
  if (cbt > rbt) return;
  __shared__ float A[64][69];
  __shared__ float B[64][69];
  int tid = threadIdx.x;
  for (int i = tid; i < 64 * 64; i += 256) {
    int r = i >> 6, k = i & 63;
    A[r][k] = K[(size_t)(rbt + r) * NS + j + k];
    B[r][k] = K[(size_t)(cbt + r) * NS + j + k];
  }
  __syncthreads();
  int tx = tid & 15, ty = tid >> 4;
  float acc[4][4] = {};
  for (int k = 0; k < 64; ++k) {
    float aa[4], bb[4];
    #pragma unroll
    for (int i = 0; i < 4; ++i) aa[i] = A[ty * 4 + i][k];
    #pragma unroll
    for (int i = 0; i < 4; ++i) bb[i] = B[tx * 4 + i][k];
    #pragma unroll
    for (int i = 0; i < 4; ++i)
      #pragma unroll
      for (int jj = 0; jj < 4; ++jj)
        acc[i][jj] = fmaf(aa[i], bb[jj], acc[i][jj]);
  }
  #pragma unroll
  for (int i = 0; i < 4; ++i)
    #pragma unroll
    for (int jj = 0; jj < 4; ++jj)
      K[(size_t)(rbt + ty * 4 + i) * NS + cbt + tx * 4 + jj] -= acc[i][jj];
}

// ---------------- cho_solve: LDS-staged panels, L W = Y then L^T alpha = W ----------------
__global__ __launch_bounds__(1024) void cho_solve_kernel(const float* __restrict__ K,
                                                         const int* __restrict__ Ys,
                                                         unsigned short* __restrict__ alpha_t) {
  __shared__ float W[NS][NW];    // 32 KB
  __shared__ float P[64][68];    // staged 64x64 panel (padded, float4-aligned)
  __shared__ float invd[64];
  const int tid = threadIdx.x;
  const int rr = tid >> 4, nn = tid & 15;
  const int pcol = (tid & 15) * 4;

  for (int i = tid; i < NS * NW; i += 1024)
    W[i >> 4][i & 15] = (Ys[i >> 4] == (i & 15)) ? 1.f : 0.f;

  // ---- forward: L W = Y ----
  for (int jb = 0; jb < 8; ++jb) {
    const int j = jb << 6;
    __syncthreads();
    *(float4*)&P[rr][pcol] = *(const float4*)(K + (size_t)(j + rr) * NS + j + pcol);
    __syncthreads();
    if (tid < 64) invd[tid] = 1.f / P[tid][tid];
    __syncthreads();
    if (tid < 64) {  // wave-lockstep diag solve
      int n = tid & 15, rq = tid >> 4;
      float w[16];
      #pragma unroll
      for (int i = 0; i < 16; ++i) w[i] = W[j + rq + 4 * i][n];
      #pragma unroll
      for (int c = 0; c < 64; ++c) {
        float xc = __shfl(w[c >> 2], ((c & 3) << 4) + n) * invd[c];
        if (rq == (c & 3)) w[c >> 2] = xc;
        #pragma unroll
        for (int i = 0; i < 16; ++i) {
          int r = rq + 4 * i;
          if (r > c) w[i] -= P[r][c] * xc;
        }
      }
      #pragma unroll
      for (int i = 0; i < 16; ++i) W[j + rq + 4 * i][n] = w[i];
    }
    __syncthreads();
    // update rows below: stage 64-row panel chunk, rank-64 update from LDS
    for (int r0 = j + 64; r0 < NS; r0 += 64) {
      __syncthreads();
      *(float4*)&P[rr][pcol] = *(const float4*)(K + (size_t)(r0 + rr) * NS + j + pcol);
      __syncthreads();
      float s = W[r0 + rr][nn];
      #pragma unroll
      for (int c = 0; c < 64; c += 4) {
        float4 p = *(const float4*)&P[rr][c];
        s -= p.x * W[j + c + 0][nn] + p.y * W[j + c + 1][nn]
           + p.z * W[j + c + 2][nn] + p.w * W[j + c + 3][nn];
      }
      W[r0 + rr][nn] = s;
    }
  }
  // ---- backward: L^T alpha = W ----
  for (int jb = 7; jb >= 0; --jb) {
    const int j = jb << 6;
    __syncthreads();
    *(float4*)&P[rr][pcol] = *(const float4*)(K + (size_t)(j + rr) * NS + j + pcol);
    __syncthreads();
    if (tid < 64) invd[tid] = 1.f / P[tid][tid];
    __syncthreads();
    if (tid < 64) {
      int n = tid & 15, rq = tid >> 4;
      float w[16];
      #pragma unroll
      for (int i = 0; i < 16; ++i) w[i] = W[j + rq + 4 * i][n];
      #pragma unroll
      for (int c = 63; c >= 0; --c) {
        float xc = __shfl(w[c >> 2], ((c & 3) << 4) + n) * invd[c];
        if (rq == (c & 3)) w[c >> 2] = xc;
        #pragma unroll
        for (int i = 0; i < 16; ++i) {
          int r = rq + 4 * i;
          if (r < c) w[i] -= P[c][r] * xc;
        }
      }
      #pragma unroll
      for (int i = 0; i < 16; ++i) W[j + rq + 4 * i][n] = w[i];
    }
    __syncthreads();
    // update rows above: stage L[j..j+64][r0..r0+64] (transposed use)
    for (int r0 = j - 64; r0 >= 0; r0 -= 64) {
      __syncthreads();
      *(float4*)&P[rr][pcol] = *(const float4*)(K + (size_t)(j + rr) * NS + r0 + pcol);
      __syncthreads();
      float s = W[r0 + rr][nn];
      #pragma unroll
      for (int c = 0; c < 64; ++c)
        s -= P[c][rr] * W[j + c][nn];
      W[r0 + rr][nn] = s;
    }
  }
  __syncthreads();
  for (int i = tid; i < NS * NW; i += 1024)
    alpha_t[(size_t)(i & 15) * NS + (i >> 4)] = bf_rne(W[i >> 4][i & 15]);
}

// ---------------- fused: split-bf16 MFMA Gram -> exp -> MFMA PV -> softmax ----------------
__global__ __launch_bounds__(512) void fused_v2(const float* __restrict__ Zq,
                                                const float* __restrict__ Zs,
                                                const float* __restrict__ sn,
                                                const unsigned short* __restrict__ alpha_t,
                                                const float* __restrict__ log_ls,
                                                float* __restrict__ out) {
  __shared__ __align__(16) unsigned short LB[32768];  // 64 KB, unioned
  __shared__ float qnl[128];
  __shared__ float snl[256];
  unsigned short* AhB = LB;            // Zq hi  [128][32]
  unsigned short* AlB = LB + 4096;     // Zq lo
  unsigned short* BhB = LB + 8192;     // Zs hi  [256][32]
  unsigned short* BlB = LB + 16384;    // Zs lo
  unsigned short* KqB = LB;            // Kq bf16 [128][256] (epilogue overlay)

  const int tid = threadIdx.x;
  const int lane = tid & 63;
  const int w = tid >> 6;              // 8 waves: 2(m) x 4(n)
  const int wm = w >> 2, wn = w & 3;
  const int l15 = lane & 15, l4 = lane >> 4;
  const int rb = blockIdx.x * 128;
  const float inv2 = 0.5f * __expf(-2.f * log_ls[0]);
  const unsigned swz = (unsigned)((l15 & 7) << 3);

  if (tid < 128) qnl[tid] = 0.f;
  __syncthreads();

  const int qrow0 = tid >> 3;          // 0..63
  const int qk0 = (tid & 7) * 4;
  const int qrow1 = 64 + qrow0;

  floatx4 facc = {0.f, 0.f, 0.f, 0.f};

  for (int cc = 0; cc < NS; cc += 256) {
    if (tid < 256) snl[tid] = sn[cc + tid];
    floatx4 acc[4][4];
    #pragma unroll
    for (int a = 0; a < 4; ++a)
      #pragma unroll
      for (int b = 0; b < 4; ++b) acc[a][b] = (floatx4){0.f, 0.f, 0.f, 0.f};

    // prefetch kt = 0
    float4 pq0 = *(const float4*)(Zq + (size_t)(rb + qrow0) * DD + qk0);
    float4 pq1 = *(const float4*)(Zq + (size_t)(rb + qrow1) * DD + qk0);
    float4 ps[4];
    #pragma unroll
    for (int u = 0; u < 4; ++u) {
      int idx = tid + (u << 9);
      ps[u] = *(const float4*)(Zs + (size_t)(cc + (idx >> 3)) * DD + ((idx & 7) * 4));
    }

    for (int kt = 0; kt < 32; ++kt) {
      // ---- STORE phase: regs -> swizzled split-bf16 LDS ----
      STASH(AhB, AlB, qrow0, qk0, pq0);
      STASH(AhB, AlB, qrow1, qk0, pq1);
      #pragma unroll
      for (int u = 0; u < 4; ++u) {
        int idx = tid + (u << 9);
        int srow = idx >> 3, sk0 = (idx & 7) * 4;
        STASH(BhB, BlB, srow, sk0, ps[u]);
      }
      if (cc == 0) {  // fold Zq row-norm accumulation into chunk-0 staging
        float s0 = pq0.x * pq0.x + pq0.y * pq0.y + pq0.z * pq0.z + pq0.w * pq0.w;
        float s1 = pq1.x * pq1.x + pq1.y * pq1.y + pq1.z * pq1.z + pq1.w * pq1.w;
        #pragma unroll
        for (int d = 1; d < 8; d <<= 1) { s0 += __shfl_xor(s0, d); s1 += __shfl_xor(s1, d); }
        if ((tid & 7) == 0) { qnl[qrow0] += s0; qnl[qrow1] += s1; }
      }
      __syncthreads();
      // ---- prefetch next iter (hidden under MFMA) ----
      if (kt < 31) {
        int kk2 = (kt + 1) << 5;
        pq0 = *(const float4*)(Zq + (size_t)(rb + qrow0) * DD + kk2 + qk0);
        pq1 = *(const float4*)(Zq + (size_t)(rb + qrow1) * DD + kk2 + qk0);
        #pragma unroll
        for (int u = 0; u < 4; ++u) {
          int idx = tid + (u << 9);
          ps[u] = *(const float4*)(Zs + (size_t)(cc + (idx >> 3)) * DD + kk2 + ((idx & 7) * 4));
        }
      }
      // ---- compute: 16 ds_read_b128 + 48 MFMA ----
      short8x ah[4], al[4], bh[4], bl[4];
      #pragma unroll
      for (int mi = 0; mi < 4; ++mi) {
        unsigned e = (unsigned)((wm * 64 + mi * 16 + l15) * 32 + 8 * l4) ^ swz;
        ah[mi] = *(const short8x*)&AhB[e];
        al[mi] = *(const short8x*)&AlB[e];
      }
      #pragma unroll
      for (int ni = 0; ni < 4; ++ni) {
        unsigned e = (unsigned)((wn * 64 + ni * 16 + l15) * 32 + 8 * l4) ^ swz;
        bh[ni] = *(const short8x*)&BhB[e];
        bl[ni] = *(const short8x*)&BlB[e];
      }
      #pragma unroll
      for (int mi = 0; mi < 4; ++mi)
        #pragma unroll
        for (int ni = 0; ni < 4; ++ni) {
          acc[mi][ni] = __builtin_amdgcn_mfma_f32_16x16x32_bf16(ah[mi], bh[ni], acc[mi][ni], 0, 0, 0);
          acc[mi][ni] = __builtin_amdgcn_mfma_f32_16x16x32_bf16(ah[mi], bl[ni], acc[mi][ni], 0, 0, 0);
          acc[mi][ni] = __builtin_amdgcn_mfma_f32_16x16x32_bf16(al[mi], bh[ni], acc[mi][ni], 0, 0, 0);
        }
      __syncthreads();
    }

    // ---- epilogue: PV B-frags (alpha^T, global/L2), kq -> KqB, PV MFMA ----
    short8x bfr[8];
    #pragma unroll
    for (int s = 0; s < 8; ++s)
      bfr[s] = *(const short8x*)(alpha_t + ((size_t)l15 * NS + cc + 32 * s + 8 * l4));

    #pragma unroll
    for (int mi = 0; mi < 4; ++mi)
      #pragma unroll
      for (int rr = 0; rr < 4; ++rr) {
        int row_l = wm * 64 + mi * 16 + l4 * 4 + rr;
        float qv = qnl[row_l];
        unsigned sw = (unsigned)((row_l & 7) << 3);
        #pragma unroll
        for (int ni = 0; ni < 4; ++ni) {
          int col = wn * 64 + ni * 16 + l15;
          float d2 = fmaxf(qv + snl[col] - 2.f * acc[mi][ni][rr], 0.f);
          float kq = __expf(-d2 * inv2);
          KqB[(unsigned)(row_l * 256 + col) ^ sw] = bf_rne(kq);
        }
      }
    __syncthreads();
    #pragma unroll
    for (int s = 0; s < 8; ++s) {
      unsigned e = (unsigned)((w * 16 + l15) * 256 + 32 * s + 8 * l4) ^ swz;
      short8x ak = *(const short8x*)&KqB[e];
      facc = __builtin_amdgcn_mfma_f32_16x16x32_bf16(ak, bfr[s], facc, 0, 0, 0);
    }
    __syncthreads();
  }

  // ---- softmax over 16 classes (spread across 16-lane groups) ----
  #pragma unroll
  for (int r = 0; r < 4; ++r) {
    float v = facc[r];
    float m = v;
    #pragma unroll
    for (int d = 1; d < 16; d <<= 1) m = fmaxf(m, __shfl_xor(m, d));
    float e = __expf(v - m);
    float s = e;
    #pragma unroll
    for (int d = 1; d < 16; d <<= 1) s += __shfl_xor(s, d);
    out[(size_t)(rb + w * 16 + l4 * 4 + r) * NW + l15] = e / s;
  }
}

extern "C" void kernel_launch(void* const* d_in, const int* in_sizes, int n_in,
                              void* d_out, int out_size, void* d_ws, size_t ws_size,
                              hipStream_t stream) {
  (void)in_sizes; (void)n_in; (void)out_size; (void)ws_size;
  const float* Zs = (const float*)d_in[0];
  const int*   Ys = (const int*)d_in[1];
  const float* Zq = (const float*)d_in[2];
  const float* log_ls = (const float*)d_in[3];
  const float* log_noise = (const float*)d_in[4];
  float* out = (float*)d_out;

  float* ws = (float*)d_ws;
  float* K  = ws;                                   // 512*512 f32
  float* sn = ws + (size_t)NS * NS;                 // 512 f32
  unsigned short* alpha_t = (unsigned short*)(sn + NS);  // [16][512] bf16

  row_norms_kernel<<<128, 256, 0, stream>>>(Zs, sn, NS);
  kss_kernel<<<dim3(8, 8), 256, 0, stream>>>(Zs, sn, log_ls, log_noise, K);
  for (int j = 0; j < NS; j += 64) {
    chol_panel<<<1, 512, 0, stream>>>(K, j);
    int rows = NS - j - 64;
    if (rows > 0) {
      int t = rows / 64;
      syrk_trailing<<<dim3(t, t), 256, 0, stream>>>(K, j);
    }
  }
  cho_solve_kernel<<<1, 1024, 0, stream>>>(K, Ys, alpha_t);
  fused_v2<<<NQ / 128, 512, 0, stream>>>(Zq, Zs, sn, alpha_t, log_ls, out);
}

// Round 4
// 1403.931 us; speedup vs baseline: 1.9983x; 1.1784x over previous
//
#include <hip/hip_runtime.h>
#include <math.h>

#define NS 512      // N_way*K_shot support samples
#define NQ 65536    // N_way*Q_query rows
#define DD 1024     // feature dim
#define NW 16       // N_way

typedef __attribute__((ext_vector_type(8))) short short8x;
typedef __attribute__((ext_vector_type(4))) float floatx4;

static __device__ __forceinline__ unsigned short bf_trunc(float x) {
  return (unsigned short)(__float_as_uint(x) >> 16);
}
static __device__ __forceinline__ float bf_tof(unsigned short h) {
  return __uint_as_float(((unsigned)h) << 16);
}
static __device__ __forceinline__ unsigned short bf_rne(float x) {
  unsigned u = __float_as_uint(x);
  return (unsigned short)((u + 0x7FFFu + ((u >> 16) & 1u)) >> 16);
}

// split f32 -> (hi, lo) bf16 pair, swizzled 8B LDS store. k0 multiple of 4.
#define STASH(Hp, Lp, row, k0, v) do {                                      \
    unsigned e_ = (unsigned)((((row) * 32 + (k0)) ^ (((row) & 7) << 3)));   \
    ushort4 h_, l_;                                                         \
    h_.x = bf_trunc((v).x); l_.x = bf_trunc((v).x - bf_tof(h_.x));          \
    h_.y = bf_trunc((v).y); l_.y = bf_trunc((v).y - bf_tof(h_.y));          \
    h_.z = bf_trunc((v).z); l_.z = bf_trunc((v).z - bf_tof(h_.z));          \
    h_.w = bf_trunc((v).w); l_.w = bf_trunc((v).w - bf_tof(h_.w));          \
    *(ushort4*)&Hp[e_] = h_; *(ushort4*)&Lp[e_] = l_;                       \
  } while (0)

// ---------------- row squared-norms (wave per row) — Zs only ----------------
__global__ void row_norms_kernel(const float* __restrict__ X, float* __restrict__ out, int nrows) {
  int gw = (int)((blockIdx.x * blockDim.x + threadIdx.x) >> 6);
  int lane = threadIdx.x & 63;
  if (gw >= nrows) return;
  const float* row = X + (size_t)gw * DD;
  float s = 0.f;
  #pragma unroll
  for (int i = 0; i < 4; ++i) {
    float4 v = *(const float4*)(row + 4 * lane + 256 * i);
    s += v.x * v.x + v.y * v.y + v.z * v.z + v.w * v.w;
  }
  #pragma unroll
  for (int off = 32; off; off >>= 1) s += __shfl_xor(s, off);
  if (lane == 0) out[gw] = s;
}

// ---------------- Kss = rbf(Zs,Zs) + noise*I  (64x64 tiles, fp32 exact) ----------------
__global__ __launch_bounds__(256) void kss_kernel(const float* __restrict__ Zs,
                                                  const float* __restrict__ sn,
                                                  const float* __restrict__ log_ls,
                                                  const float* __restrict__ log_noise,
                                                  float* __restrict__ K) {
  __shared__ __align__(16) float At[16][68];
  __shared__ __align__(16) float Bt[16][68];
  int tid = threadIdx.x;
  int rb = blockIdx.y * 64, cb = blockIdx.x * 64;
  int tx = tid & 15, ty = tid >> 4;
  int srow = tid & 63, skq = (tid >> 6) << 2;
  float acc[4][4] = {};
  for (int kk = 0; kk < DD; kk += 16) {
    __syncthreads();
    float4 a = *(const float4*)(Zs + (size_t)(rb + srow) * DD + kk + skq);
    float4 b = *(const float4*)(Zs + (size_t)(cb + srow) * DD + kk + skq);
    At[skq + 0][srow] = a.x; At[skq + 1][srow] = a.y; At[skq + 2][srow] = a.z; At[skq + 3][srow] = a.w;
    Bt[skq + 0][srow] = b.x; Bt[skq + 1][srow] = b.y; Bt[skq + 2][srow] = b.z; Bt[skq + 3][srow] = b.w;
    __syncthreads();
    #pragma unroll
    for (int k = 0; k < 16; ++k) {
      float4 av = *(const float4*)&At[k][ty * 4];
      float4 bv = *(const float4*)&Bt[k][tx * 4];
      float aa[4] = {av.x, av.y, av.z, av.w};
      float bb[4] = {bv.x, bv.y, bv.z, bv.w};
      #pragma unroll
      for (int i = 0; i < 4; ++i)
        #pragma unroll
        for (int j = 0; j < 4; ++j)
          acc[i][j] = fmaf(aa[i], bb[j], acc[i][j]);
    }
  }
  float inv2 = 0.5f * expf(-2.f * log_ls[0]);
  float noise = expf(2.f * log_noise[0]);
  #pragma unroll
  for (int i = 0; i < 4; ++i)
    #pragma unroll
    for (int j = 0; j < 4; ++j) {
      int r = rb + ty * 4 + i, c = cb + tx * 4 + j;
      float d2 = fmaxf(sn[r] + sn[c] - 2.f * acc[i][j], 0.f);
      float v = expf(-d2 * inv2);
      if (r == c) v += noise;
      K[(size_t)r * NS + c] = v;
    }
}

// ---------------- fused panel: potrf(64x64 diag) + trsm(rows below) ----------------
__global__ __launch_bounds__(512) void chol_panel(float* __restrict__ K, int j) {
  __shared__ float A[64][65];
  __shared__ float diag[64], idia[64];
  int tid = threadIdx.x;
  for (int i = tid; i < 4096; i += 512) {
    int r = i >> 6, c = i & 63;
    A[r][c] = K[(size_t)(j + r) * NS + j + c];
  }
  __syncthreads();
  for (int c = 0; c < 64; ++c) {
    float d = A[c][c];
    float s = sqrtf(d);
    float inv = 1.f / s;
    if (tid == c) { diag[c] = s; idia[c] = inv; }
    if (tid < 64 && tid > c) A[tid][c] *= inv;
    __syncthreads();
    for (int i = tid; i < 4096; i += 512) {
      int r = i >> 6, k = i & 63;
      if (r > c && k > c) A[r][k] -= A[r][c] * A[k][c];
    }
    __syncthreads();
  }
  for (int i = tid; i < 4096; i += 512) {
    int r = i >> 6, c = i & 63;
    if (c <= r) K[(size_t)(j + r) * NS + j + c] = (c == r) ? diag[r] : A[r][c];
  }
  // trsm: rows below panel solve X * L11^T = A21 (one row per thread)
  for (int r0 = j + 64 + tid; r0 < NS; r0 += 512) {
    float x[64];
    #pragma unroll
    for (int c = 0; c < 64; ++c) {
      float v = K[(size_t)r0 * NS + j + c];
      #pragma unroll
      for (int k = 0; k < c; ++k) v -= x[k] * A[c][k];
      x[c] = v * idia[c];
    }
    #pragma unroll
    for (int c = 0; c < 64; ++c) K[(size_t)r0 * NS + j + c] = x[c];
  }
}

// trailing update A22 -= L21 * L21^T (64x64 tiles, skip strictly-upper tiles)
__global__ __launch_bounds__(256) void syrk_trailing(float* __restrict__ K, int j) {
  int t0 = j + 64;
  int rbt = t0 + blockIdx.y * 64, cbt = t0 + blockIdx.x * 64;
  if (cbt > rbt) return;
  __shared__ float A[64][69];
  __shared__ float B[64][69];
  int tid = threadIdx.x;
  for (int i = tid; i < 64 * 64; i += 256) {
    int r = i >> 6, k = i & 63;
    A[r][k] = K[(size_t)(rbt + r) * NS + j + k];
    B[r][k] = K[(size_t)(cbt + r) * NS + j + k];
  }
  __syncthreads();
  int tx = tid & 15, ty = tid >> 4;
  float acc[4][4] = {};
  for (int k = 0; k < 64; ++k) {
    float aa[4], bb[4];
    #pragma unroll
    for (int i = 0; i < 4; ++i) aa[i] = A[ty * 4 + i][k];
    #pragma unroll
    for (int i = 0; i < 4; ++i) bb[i] = B[tx * 4 + i][k];
    #pragma unroll
    for (int i = 0; i < 4; ++i)
      #pragma unroll
      for (int jj = 0; jj < 4; ++jj)
        acc[i][jj] = fmaf(aa[i], bb[jj], acc[i][jj]);
  }
  #pragma unroll
  for (int i = 0; i < 4; ++i)
    #pragma unroll
    for (int jj = 0; jj < 4; ++jj)
      K[(size_t)(rbt + ty * 4 + i) * NS + cbt + tx * 4 + jj] -= acc[i][jj];
}

// ---------------- fill strictly-upper triangle of K with L^T ----------------
__global__ __launch_bounds__(256) void transpose_fill(float* __restrict__ K) {
  int bx = blockIdx.x, by = blockIdx.y;
  if (by < bx) return;                 // source tiles: lower-or-diag only
  int rb = by * 64, cb = bx * 64;
  __shared__ float T[64][65];
  int tid = threadIdx.x;
  int rr = tid >> 4, pc = (tid & 15) * 4;
  #pragma unroll
  for (int u = 0; u < 4; ++u) {
    int r = rr + 16 * u;
    *(float4*)&T[r][pc] = *(const float4*)(K + (size_t)(rb + r) * NS + cb + pc);
  }
  __syncthreads();
  if (by == bx) {
    #pragma unroll
    for (int u = 0; u < 4; ++u) {
      int r = rr + 16 * u;
      #pragma unroll
      for (int i = 0; i < 4; ++i) {
        int c = pc + i;
        if (c > r) K[(size_t)(rb + r) * NS + cb + c] = T[c][r];
      }
    }
  } else {
    #pragma unroll
    for (int u = 0; u < 4; ++u) {
      int orr = rr + 16 * u;           // row within destination (cb) tile
      float4 o;
      o.x = T[pc + 0][orr]; o.y = T[pc + 1][orr];
      o.z = T[pc + 2][orr]; o.w = T[pc + 3][orr];
      *(float4*)(K + (size_t)(cb + orr) * NS + rb + pc) = o;
    }
  }
}

// ---------------- cho_solve v2: W in registers, L2-direct panel reads ----------------
// thread (rs,nn): rs=tid>>4 (0..63), nn=tid&15; owns w[k] = W[rs+64k][nn], k=0..7.
// K lower = L, K strictly-upper = L^T (from transpose_fill).
__global__ __launch_bounds__(1024) void cho_solve_v2(const float* __restrict__ K,
                                                     const int* __restrict__ Ys,
                                                     unsigned short* __restrict__ alpha_t) {
  __shared__ float P[64][68];
  __shared__ float WsT[16][68];
  __shared__ float Wblk[64][16];
  __shared__ float invd[64];
  const int tid = threadIdx.x;
  const int rs = tid >> 4, nn = tid & 15;
  const int pc = nn * 4;

  float w[8];
  #pragma unroll
  for (int k = 0; k < 8; ++k) w[k] = (Ys[rs + 64 * k] == nn) ? 1.f : 0.f;

  // ---- forward: L W = Y ----
  for (int jb = 0; jb < 8; ++jb) {
    const int j = jb << 6;
    __syncthreads();
    #pragma unroll
    for (int k = 0; k < 8; ++k) if (k == jb) Wblk[rs][nn] = w[k];
    *(floatx4*)&P[rs][pc] = *(const floatx4*)(K + (size_t)(j + rs) * NS + j + pc);
    __syncthreads();
    if (tid < 64) {                    // wave-0 lockstep diag solve
      const int n = tid & 15, rq = tid >> 4;
      invd[tid] = 1.f / P[tid][tid];
      float w16[16];
      #pragma unroll
      for (int i = 0; i < 16; ++i) w16[i] = Wblk[rq + 4 * i][n];
      #pragma unroll
      for (int g = 0; g < 16; ++g) {
        floatx4 p[16];
        #pragma unroll
        for (int i = 0; i < 16; ++i) p[i] = *(const floatx4*)&P[rq + 4 * i][4 * g];
        #pragma unroll
        for (int cj = 0; cj < 4; ++cj) {
          const int c = 4 * g + cj;
          float xc = __shfl(w16[c >> 2], ((c & 3) << 4) + n) * invd[c];
          if (rq == (c & 3)) w16[c >> 2] = xc;
          #pragma unroll
          for (int i = 0; i < 16; ++i) {
            int r = rq + 4 * i;
            if (r > c) w16[i] -= p[i][cj] * xc;
          }
        }
      }
      #pragma unroll
      for (int i = 0; i < 16; ++i) WsT[n][rq + 4 * i] = w16[i];
    }
    __syncthreads();
    #pragma unroll
    for (int k = 0; k < 8; ++k) if (k == jb) w[k] = WsT[nn][rs];
    floatx4 wsr[16];
    #pragma unroll
    for (int g = 0; g < 16; ++g) wsr[g] = *(const floatx4*)&WsT[nn][4 * g];
    #pragma unroll
    for (int k = 0; k < 8; ++k) {
      if (k > jb) {
        const float* lrow = K + (size_t)(rs + 64 * k) * NS + j;
        float s = w[k];
        #pragma unroll
        for (int g = 0; g < 16; ++g) {
          floatx4 lv = *(const floatx4*)(lrow + 4 * g);
          s -= lv.x * wsr[g].x + lv.y * wsr[g].y + lv.z * wsr[g].z + lv.w * wsr[g].w;
        }
        w[k] = s;
      }
    }
  }

  // ---- backward: L^T alpha = W ----
  for (int jb = 7; jb >= 0; --jb) {
    const int j = jb << 6;
    __syncthreads();
    #pragma unroll
    for (int k = 0; k < 8; ++k) if (k == jb) Wblk[rs][nn] = w[k];
    *(floatx4*)&P[rs][pc] = *(const floatx4*)(K + (size_t)(j + rs) * NS + j + pc);
    __syncthreads();
    if (tid < 64) {                    // upper-tri solve, columns descending
      const int n = tid & 15, rq = tid >> 4;
      invd[tid] = 1.f / P[tid][tid];
      float w16[16];
      #pragma unroll
      for (int i = 0; i < 16; ++i) w16[i] = Wblk[rq + 4 * i][n];
      #pragma unroll
      for (int g = 15; g >= 0; --g) {
        floatx4 p[16];
        #pragma unroll
        for (int i = 0; i < 16; ++i) p[i] = *(const floatx4*)&P[rq + 4 * i][4 * g];
        #pragma unroll
        for (int cj = 3; cj >= 0; --cj) {
          const int c = 4 * g + cj;
          float xc = __shfl(w16[c >> 2], ((c & 3) << 4) + n) * invd[c];
          if (rq == (c & 3)) w16[c >> 2] = xc;
          #pragma unroll
          for (int i = 0; i < 16; ++i) {
            int r = rq + 4 * i;
            if (r < c) w16[i] -= p[i][cj] * xc;
          }
        }
      }
      #pragma unroll
      for (int i = 0; i < 16; ++i) WsT[n][rq + 4 * i] = w16[i];
    }
    __syncthreads();
    #pragma unroll
    for (int k = 0; k < 8; ++k) if (k == jb) w[k] = WsT[nn][rs];
    floatx4 wsr[16];
    #pragma unroll
    for (int g = 0; g < 16; ++g) wsr[g] = *(const floatx4*)&WsT[nn][4 * g];
    #pragma unroll
    for (int k = 0; k < 8; ++k) {
      if (k < jb) {                    // rows above: read L^T from upper triangle
        const float* lrow = K + (size_t)(rs + 64 * k) * NS + j;
        float s = w[k];
        #pragma unroll
        for (int g = 0; g < 16; ++g) {
          floatx4 lv = *(const floatx4*)(lrow + 4 * g);
          s -= lv.x * wsr[g].x + lv.y * wsr[g].y + lv.z * wsr[g].z + lv.w * wsr[g].w;
        }
        w[k] = s;
      }
    }
  }

  #pragma unroll
  for (int k = 0; k < 8; ++k)
    alpha_t[(size_t)nn * NS + rs + 64 * k] = bf_rne(w[k]);
}

// ---------------- fused: split-bf16 MFMA Gram -> exp -> MFMA PV -> softmax ----------------
__global__ __launch_bounds__(512) void fused_v2(const float* __restrict__ Zq,
                                                const float* __restrict__ Zs,
                                                const float* __restrict__ sn,
                                                const unsigned short* __restrict__ alpha_t,
                                                const float* __restrict__ log_ls,
                                                float* __restrict__ out) {
  __shared__ __align__(16) unsigned short LB[32768];  // 64 KB, unioned
  __shared__ float qnl[128];
  __shared__ float snl[256];
  unsigned short* AhB = LB;            // Zq hi  [128][32]
  unsigned short* AlB = LB + 4096;     // Zq lo
  unsigned short* BhB = LB + 8192;     // Zs hi  [256][32]
  unsigned short* BlB = LB + 16384;    // Zs lo
  unsigned short* KqB = LB;            // Kq bf16 [128][256] (epilogue overlay)

  const int tid = threadIdx.x;
  const int lane = tid & 63;
  const int w = tid >> 6;              // 8 waves: 2(m) x 4(n)
  const int wm = w >> 2, wn = w & 3;
  const int l15 = lane & 15, l4 = lane >> 4;
  const int rb = blockIdx.x * 128;
  const float inv2 = 0.5f * __expf(-2.f * log_ls[0]);
  const unsigned swz = (unsigned)((l15 & 7) << 3);

  if (tid < 128) qnl[tid] = 0.f;
  __syncthreads();

  const int qrow0 = tid >> 3;          // 0..63
  const int qk0 = (tid & 7) * 4;
  const int qrow1 = 64 + qrow0;

  floatx4 facc = {0.f, 0.f, 0.f, 0.f};

  for (int cc = 0; cc < NS; cc += 256) {
    if (tid < 256) snl[tid] = sn[cc + tid];
    floatx4 acc[4][4];
    #pragma unroll
    for (int a = 0; a < 4; ++a)
      #pragma unroll
      for (int b = 0; b < 4; ++b) acc[a][b] = (floatx4){0.f, 0.f, 0.f, 0.f};

    // prefetch kt = 0
    float4 pq0 = *(const float4*)(Zq + (size_t)(rb + qrow0) * DD + qk0);
    float4 pq1 = *(const float4*)(Zq + (size_t)(rb + qrow1) * DD + qk0);
    float4 ps[4];
    #pragma unroll
    for (int u = 0; u < 4; ++u) {
      int idx = tid + (u << 9);
      ps[u] = *(const float4*)(Zs + (size_t)(cc + (idx >> 3)) * DD + ((idx & 7) * 4));
    }

    for (int kt = 0; kt < 32; ++kt) {
      // ---- STORE phase: regs -> swizzled split-bf16 LDS ----
      STASH(AhB, AlB, qrow0, qk0, pq0);
      STASH(AhB, AlB, qrow1, qk0, pq1);
      #pragma unroll
      for (int u = 0; u < 4; ++u) {
        int idx = tid + (u << 9);
        int srow = idx >> 3, sk0 = (idx & 7) * 4;
        STASH(BhB, BlB, srow, sk0, ps[u]);
      }
      if (cc == 0) {  // fold Zq row-norm accumulation into chunk-0 staging
        float s0 = pq0.x * pq0.x + pq0.y * pq0.y + pq0.z * pq0.z + pq0.w * pq0.w;
        float s1 = pq1.x * pq1.x + pq1.y * pq1.y + pq1.z * pq1.z + pq1.w * pq1.w;
        #pragma unroll
        for (int d = 1; d < 8; d <<= 1) { s0 += __shfl_xor(s0, d); s1 += __shfl_xor(s1, d); }
        if ((tid & 7) == 0) { qnl[qrow0] += s0; qnl[qrow1] += s1; }
      }
      __syncthreads();
      // ---- prefetch next iter (hidden under MFMA) ----
      if (kt < 31) {
        int kk2 = (kt + 1) << 5;
        pq0 = *(const float4*)(Zq + (size_t)(rb + qrow0) * DD + kk2 + qk0);
        pq1 = *(const float4*)(Zq + (size_t)(rb + qrow1) * DD + kk2 + qk0);
        #pragma unroll
        for (int u = 0; u < 4; ++u) {
          int idx = tid + (u << 9);
          ps[u] = *(const float4*)(Zs + (size_t)(cc + (idx >> 3)) * DD + kk2 + ((idx & 7) * 4));
        }
      }
      // ---- compute: 16 ds_read_b128 + 48 MFMA ----
      short8x ah[4], al[4], bh[4], bl[4];
      #pragma unroll
      for (int mi = 0; mi < 4; ++mi) {
        unsigned e = (unsigned)((wm * 64 + mi * 16 + l15) * 32 + 8 * l4) ^ swz;
        ah[mi] = *(const short8x*)&AhB[e];
        al[mi] = *(const short8x*)&AlB[e];
      }
      #pragma unroll
      for (int ni = 0; ni < 4; ++ni) {
        unsigned e = (unsigned)((wn * 64 + ni * 16 + l15) * 32 + 8 * l4) ^ swz;
        bh[ni] = *(const short8x*)&BhB[e];
        bl[ni] = *(const short8x*)&BlB[e];
      }
      #pragma unroll
      for (int mi = 0; mi < 4; ++mi)
        #pragma unroll
        for (int ni = 0; ni < 4; ++ni) {
          acc[mi][ni] = __builtin_amdgcn_mfma_f32_16x16x32_bf16(ah[mi], bh[ni], acc[mi][ni], 0, 0, 0);
          acc[mi][ni] = __builtin_amdgcn_mfma_f32_16x16x32_bf16(ah[mi], bl[ni], acc[mi][ni], 0, 0, 0);
          acc[mi][ni] = __builtin_amdgcn_mfma_f32_16x16x32_bf16(al[mi], bh[ni], acc[mi][ni], 0, 0, 0);
        }
      __syncthreads();
    }

    // ---- epilogue: PV B-frags (alpha^T, global/L2), kq -> KqB, PV MFMA ----
    short8x bfr[8];
    #pragma unroll
    for (int s = 0; s < 8; ++s)
      bfr[s] = *(const short8x*)(alpha_t + ((size_t)l15 * NS + cc + 32 * s + 8 * l4));

    #pragma unroll
    for (int mi = 0; mi < 4; ++mi)
      #pragma unroll
      for (int rr = 0; rr < 4; ++rr) {
        int row_l = wm * 64 + mi * 16 + l4 * 4 + rr;
        float qv = qnl[row_l];
        unsigned sw = (unsigned)((row_l & 7) << 3);
        #pragma unroll
        for (int ni = 0; ni < 4; ++ni) {
          int col = wn * 64 + ni * 16 + l15;
          float d2 = fmaxf(qv + snl[col] - 2.f * acc[mi][ni][rr], 0.f);
          float kq = __expf(-d2 * inv2);
          KqB[(unsigned)(row_l * 256 + col) ^ sw] = bf_rne(kq);
        }
      }
    __syncthreads();
    #pragma unroll
    for (int s = 0; s < 8; ++s) {
      unsigned e = (unsigned)((w * 16 + l15) * 256 + 32 * s + 8 * l4) ^ swz;
      short8x ak = *(const short8x*)&KqB[e];
      facc = __builtin_amdgcn_mfma_f32_16x16x32_bf16(ak, bfr[s], facc, 0, 0, 0);
    }
    __syncthreads();
  }

  // ---- softmax over 16 classes (spread across 16-lane groups) ----
  #pragma unroll
  for (int r = 0; r < 4; ++r) {
    float v = facc[r];
    float m = v;
    #pragma unroll
    for (int d = 1; d < 16; d <<= 1) m = fmaxf(m, __shfl_xor(m, d));
    float e = __expf(v - m);
    float s = e;
    #pragma unroll
    for (int d = 1; d < 16; d <<= 1) s += __shfl_xor(s, d);
    out[(size_t)(rb + w * 16 + l4 * 4 + r) * NW + l15] = e / s;
  }
}

extern "C" void kernel_launch(void* const* d_in, const int* in_sizes, int n_in,
                              void* d_out, int out_size, void* d_ws, size_t ws_size,
                              hipStream_t stream) {
  (void)in_sizes; (void)n_in; (void)out_size; (void)ws_size;
  const float* Zs = (const float*)d_in[0];
  const int*   Ys = (const int*)d_in[1];
  const float* Zq = (const float*)d_in[2];
  const float* log_ls = (const float*)d_in[3];
  const float* log_noise = (const float*)d_in[4];
  float* out = (float*)d_out;

  float* ws = (float*)d_ws;
  float* K  = ws;                                   // 512*512 f32
  float* sn = ws + (size_t)NS * NS;                 // 512 f32
  unsigned short* alpha_t = (unsigned short*)(sn + NS);  // [16][512] bf16

  row_norms_kernel<<<128, 256, 0, stream>>>(Zs, sn, NS);
  kss_kernel<<<dim3(8, 8), 256, 0, stream>>>(Zs, sn, log_ls, log_noise, K);
  for (int j = 0; j < NS; j += 64) {
    chol_panel<<<1, 512, 0, stream>>>(K, j);
    int rows = NS - j - 64;
    if (rows > 0) {
      int t = rows / 64;
      syrk_trailing<<<dim3(t, t), 256, 0, stream>>>(K, j);
    }
  }
  transpose_fill<<<dim3(8, 8), 256, 0, stream>>>(K);
  cho_solve_v2<<<1, 1024, 0, stream>>>(K, Ys, alpha_t);
  fused_v2<<<NQ / 128, 512, 0, stream>>>(Zq, Zs, sn, alpha_t, log_ls, out);
}